// Round 2
// baseline (340.602 us; speedup 1.0000x reference)
//
#include <hip/hip_runtime.h>
#include <stdint.h>

// ---------------------------------------------------------------------------
// Types / helpers
// ---------------------------------------------------------------------------
typedef __bf16 bf16x8 __attribute__((ext_vector_type(8)));
typedef float  f32x4  __attribute__((ext_vector_type(4)));

__device__ __forceinline__ unsigned short f2bf(float f) {
  union { float f; unsigned int u; } a; a.f = f;
  unsigned int r = a.u + 0x7FFFu + ((a.u >> 16) & 1u);   // RNE
  return (unsigned short)(r >> 16);
}

__device__ __forceinline__ unsigned short f2bf_fast(float f) {
  union { __bf16 b; unsigned short u; } v; v.b = (__bf16)f; return v.u;
}

// async global->LDS, 16B per lane. LDS dest must be wave-uniform base + lane*16.
__device__ __forceinline__ void cp16(const void* g, void* l) {
  auto g1 = reinterpret_cast<__attribute__((address_space(1))) unsigned int*>(
      reinterpret_cast<uintptr_t>(g));
  auto l3 = reinterpret_cast<__attribute__((address_space(3))) unsigned int*>(
      reinterpret_cast<uintptr_t>(l));
  __builtin_amdgcn_global_load_lds(g1, l3, 16, 0, 0);
}

// ---------------------------------------------------------------------------
// Fused: weight fp32->bf16 convert (blocks 0..12287) AND ln1+seed (blocks
// 12288..16383). Independent work, one launch to cut a kernel gap.
// ---------------------------------------------------------------------------
__global__ __launch_bounds__(256) void cvt_ln1(
    const float* __restrict__ s0, const float* __restrict__ s1,
    const float* __restrict__ s2, const float* __restrict__ s3,
    unsigned short* __restrict__ d0, unsigned short* __restrict__ d1,
    unsigned short* __restrict__ d2, unsigned short* __restrict__ d3,
    const float* __restrict__ x,
    const float* __restrict__ g,
    const float* __restrict__ bta,
    unsigned short* __restrict__ out,
    const float* __restrict__ seed_bias,
    float* __restrict__ seed_out) {
  if (blockIdx.x < 12288) {
    int i = (blockIdx.x * 256 + threadIdx.x) * 4;
    const float* src; unsigned short* dst; int off;
    if (i < 3145728)       { src = s0; dst = d0; off = 0; }
    else if (i < 4194304)  { src = s1; dst = d1; off = 3145728; }
    else if (i < 8388608)  { src = s2; dst = d2; off = 4194304; }
    else                   { src = s3; dst = d3; off = 8388608; }
    i -= off;
    float4 v = *(const float4*)(src + i);
    union { unsigned short u[4]; uint2 p; } o;
    o.u[0] = f2bf(v.x); o.u[1] = f2bf(v.y); o.u[2] = f2bf(v.z); o.u[3] = f2bf(v.w);
    *(uint2*)(dst + i) = o.p;
    return;
  }
  const int row = blockIdx.x - 12288, t = threadIdx.x;
  const float4 v = *(const float4*)(x + (size_t)row * 1024 + t * 4);
  {
    float4 sb = *(const float4*)(seed_bias + t * 4);
    float4 sv;
    sv.x = v.x + sb.x; sv.y = v.y + sb.y; sv.z = v.z + sb.z; sv.w = v.w + sb.w;
    *(float4*)(seed_out + (size_t)row * 1024 + t * 4) = sv;
  }
  float s1v = v.x + v.y + v.z + v.w;
  float s2v = v.x*v.x + v.y*v.y + v.z*v.z + v.w*v.w;
  #pragma unroll
  for (int off = 1; off < 64; off <<= 1) {
    s1v += __shfl_xor(s1v, off, 64);
    s2v += __shfl_xor(s2v, off, 64);
  }
  __shared__ float r1[4], r2[4];
  if ((t & 63) == 0) { r1[t >> 6] = s1v; r2[t >> 6] = s2v; }
  __syncthreads();
  s1v = r1[0] + r1[1] + r1[2] + r1[3];
  s2v = r2[0] + r2[1] + r2[2] + r2[3];
  const float mean = s1v * (1.0f / 1024.0f);
  const float var  = s2v * (1.0f / 1024.0f) - mean * mean;
  const float rstd = rsqrtf(var + 1e-5f);
  const float4 gv = *(const float4*)(g + t * 4);
  const float4 bv = *(const float4*)(bta + t * 4);
  union { unsigned short u[4]; uint2 p; } o;
  o.u[0] = f2bf((v.x - mean) * rstd * gv.x + bv.x);
  o.u[1] = f2bf((v.y - mean) * rstd * gv.y + bv.y);
  o.u[2] = f2bf((v.z - mean) * rstd * gv.z + bv.z);
  o.u[3] = f2bf((v.w - mean) * rstd * gv.w + bv.w);
  *(uint2*)(out + (size_t)row * 1024 + t * 4) = o.p;
}

// ---------------------------------------------------------------------------
// LayerNorm (E=1024), fp32 in -> bf16 out, PLUS seeds the next split-K GEMM's
// accumulator: seed_out[row,:] = x[row,:] + seed_bias[:].
// ---------------------------------------------------------------------------
__global__ __launch_bounds__(256) void ln_bf16_seed(
    const float* __restrict__ x,
    const float* __restrict__ g,
    const float* __restrict__ bta,
    unsigned short* __restrict__ out,
    const float* __restrict__ seed_bias,
    float* __restrict__ seed_out) {
  const int row = blockIdx.x, t = threadIdx.x;
  const float4 v = *(const float4*)(x + (size_t)row * 1024 + t * 4);
  {
    float4 sb = *(const float4*)(seed_bias + t * 4);
    float4 sv;
    sv.x = v.x + sb.x; sv.y = v.y + sb.y; sv.z = v.z + sb.z; sv.w = v.w + sb.w;
    *(float4*)(seed_out + (size_t)row * 1024 + t * 4) = sv;
  }
  float s1 = v.x + v.y + v.z + v.w;
  float s2 = v.x*v.x + v.y*v.y + v.z*v.z + v.w*v.w;
  #pragma unroll
  for (int off = 1; off < 64; off <<= 1) {
    s1 += __shfl_xor(s1, off, 64);
    s2 += __shfl_xor(s2, off, 64);
  }
  __shared__ float r1[4], r2[4];
  if ((t & 63) == 0) { r1[t >> 6] = s1; r2[t >> 6] = s2; }
  __syncthreads();
  s1 = r1[0] + r1[1] + r1[2] + r1[3];
  s2 = r2[0] + r2[1] + r2[2] + r2[3];
  const float mean = s1 * (1.0f / 1024.0f);
  const float var  = s2 * (1.0f / 1024.0f) - mean * mean;
  const float rstd = rsqrtf(var + 1e-5f);
  const float4 gv = *(const float4*)(g + t * 4);
  const float4 bv = *(const float4*)(bta + t * 4);
  union { unsigned short u[4]; uint2 p; } o;
  o.u[0] = f2bf((v.x - mean) * rstd * gv.x + bv.x);
  o.u[1] = f2bf((v.y - mean) * rstd * gv.y + bv.y);
  o.u[2] = f2bf((v.z - mean) * rstd * gv.z + bv.z);
  o.u[3] = f2bf((v.w - mean) * rstd * gv.w + bv.w);
  *(uint2*)(out + (size_t)row * 1024 + t * 4) = o.p;
}

// ---------------------------------------------------------------------------
// Pipelined GEMM core (R5 proven optimum) — kept for split-K (atomic) GEMMs.
// ---------------------------------------------------------------------------
template <int MODE>
__device__ __forceinline__ void gemm_core(
    const unsigned short* __restrict__ A,
    const unsigned short* __restrict__ Bt,
    const float* __restrict__ bias,
    void* __restrict__ outp,
    int N, int K, int kbeg, int kend,
    unsigned short* As, unsigned short* Bs) {   // each [2][128*64]
  const int tid = threadIdx.x;
  const int wave = tid >> 6, lane = tid & 63;
  const int q = lane >> 4, c = lane & 15;
  const int wm = (wave & 1) << 6, wn = (wave >> 1) << 6;
  const int m0 = blockIdx.x << 7, n0 = blockIdx.y << 7;

  const int srow = tid >> 3;                       // 0..31
  const int cg8  = ((tid & 7) ^ (srow & 7)) << 3;  // swizzled col chunk

  const unsigned short* gA = A  + (size_t)(m0 + srow) * K + cg8;
  const unsigned short* gB = Bt + (size_t)(n0 + srow) * K + cg8;
  const size_t rstep = (size_t)32 * K;

  auto issue = [&](int k0, int buf) {
    unsigned short* lA = As + buf * 8192 + tid * 8;
    unsigned short* lB = Bs + buf * 8192 + tid * 8;
    #pragma unroll
    for (int it = 0; it < 4; it++) {
      cp16(gA + it * rstep + k0, lA + it * 2048);
      cp16(gB + it * rstep + k0, lB + it * 2048);
    }
  };

  const f32x4 fzero = {0.f, 0.f, 0.f, 0.f};
  f32x4 acc[4][4];
  #pragma unroll
  for (int i = 0; i < 4; i++)
    #pragma unroll
    for (int j = 0; j < 4; j++) acc[i][j] = fzero;

  issue(kbeg, 0);
  if (kbeg + 64 < kend) issue(kbeg + 64, 1);

  int buf = 0;
  for (int k0 = kbeg; k0 < kend; k0 += 64, buf ^= 1) {
    if (k0 + 64 < kend) asm volatile("s_waitcnt vmcnt(8)" ::: "memory");
    else                asm volatile("s_waitcnt vmcnt(0)" ::: "memory");
    asm volatile("s_barrier" ::: "memory");

    const unsigned short* cA = As + buf * 8192;
    const unsigned short* cB = Bs + buf * 8192;
    #pragma unroll
    for (int ks = 0; ks < 2; ks++) {
      const int sw = (((ks << 2) + q) ^ (c & 7)) << 3;
      bf16x8 af[4], bf[4];
      #pragma unroll
      for (int i = 0; i < 4; i++) af[i] = *(const bf16x8*)&cA[(wm + i*16 + c)*64 + sw];
      #pragma unroll
      for (int j = 0; j < 4; j++) bf[j] = *(const bf16x8*)&cB[(wn + j*16 + c)*64 + sw];
      #pragma unroll
      for (int i = 0; i < 4; i++)
        #pragma unroll
        for (int j = 0; j < 4; j++)
          acc[i][j] = __builtin_amdgcn_mfma_f32_16x16x32_bf16(af[i], bf[j], acc[i][j], 0, 0, 0);
    }

    asm volatile("s_barrier" ::: "memory");
    if (k0 + 128 < kend) issue(k0 + 128, buf);
  }

  if (MODE == 4) {
    float* op = (float*)outp;
    #pragma unroll
    for (int i = 0; i < 4; i++) {
      #pragma unroll
      for (int r = 0; r < 4; r++) {
        const int row = m0 + wm + i * 16 + q * 4 + r;
        #pragma unroll
        for (int j = 0; j < 4; j++) {
          const int col = n0 + wn + j * 16 + c;
          atomicAdd(op + (size_t)row * N + col, acc[i][j][r]);
        }
      }
    }
  } else {
    float bj[4];
    #pragma unroll
    for (int j = 0; j < 4; j++) bj[j] = bias[n0 + wn + j * 16 + c];
    #pragma unroll
    for (int i = 0; i < 4; i++) {
      #pragma unroll
      for (int r = 0; r < 4; r++) {
        const int row = m0 + wm + i * 16 + q * 4 + r;
        #pragma unroll
        for (int j = 0; j < 4; j++) {
          const int col = n0 + wn + j * 16 + c;
          const size_t idx = (size_t)row * N + col;
          float v = acc[i][j][r] + bj[j];
          if (MODE == 0) ((unsigned short*)outp)[idx] = f2bf(v);
          else           ((unsigned short*)outp)[idx] = f2bf(fmaxf(v, 0.f));
        }
      }
    }
  }
}

template <int MODE>
__global__ __launch_bounds__(256, 2) void gemm_bt(
    const unsigned short* __restrict__ A,
    const unsigned short* __restrict__ Bt,
    const float* __restrict__ bias,
    void* __restrict__ outp,
    int N, int K) {
  __shared__ __align__(16) unsigned short As[2 * 8192];
  __shared__ __align__(16) unsigned short Bs[2 * 8192];
  gemm_core<MODE>(A, Bt, bias, outp, N, K, 0, K, As, Bs);
}

// split-K=2: z in {0,1}, atomicAdd into pre-seeded fp32 output
__global__ __launch_bounds__(256, 2) void gemm_bt_splitk(
    const unsigned short* __restrict__ A,
    const unsigned short* __restrict__ Bt,
    float* __restrict__ outp,
    int N, int K) {
  __shared__ __align__(16) unsigned short As[2 * 8192];
  __shared__ __align__(16) unsigned short Bs[2 * 8192];
  const int KH = K >> 1;
  const int kbeg = blockIdx.z * KH;
  gemm_core<4>(A, Bt, nullptr, outp, N, K, kbeg, kbeg + KH, As, Bs);
}

// ---------------------------------------------------------------------------
// 256x256-tile, BK=64, 8-wave (2Mx4N), 8-phase GEMM, v2.
// Per K-tile: 4 phases, quadrant order Q00->Q01->Q11->Q10 so fragment reads
// are just-in-time (12/4/8/0 per phase, 24 total = minimum) and peak live
// fragment VGPRs = 64 (v1 held all 96 live -> register-pressure regression).
// Staging: P1 t+1.A0, P2 t+1.A1 (other buffer), P3 t+2.B0, P4 t+2.B1 into
// current Bs[buf] (B reads all retired by end-P2 barrier). vmcnt(4) at P4:
// outstanding = [t+1.B(4,oldest), t+1.A(4), t+2.B(4,newest)] -> waits t+1
// fully landed, keeps t+2.B in flight. LDS 128KB, 1 block/CU, 8 waves.
// ---------------------------------------------------------------------------
template <int MODE>
__global__ __launch_bounds__(512, 2) void gemm256(
    const unsigned short* __restrict__ A,
    const unsigned short* __restrict__ Bt,
    const float* __restrict__ bias,
    unsigned short* __restrict__ outp,
    int N, int K, int nbn) {
  __shared__ __align__(16) unsigned short As[2][2][8192];   // [buf][half][128*64]
  __shared__ __align__(16) unsigned short Bs[2][2][8192];

  const int tid = threadIdx.x;
  const int wave = tid >> 6, lane = tid & 63;
  const int q = lane >> 4, c = lane & 15;
  const int wm = wave >> 2;          // A half (0..1): wave rows = wm*128..+127
  const int wn = wave & 3;           // wave cols = wn*64..+63
  const int bh = wn >> 1;            // B half
  const int bcol0 = (wn & 1) << 6;   // col base within B half

  // bijective XCD swizzle (gridDim.x % 8 == 0 for all call sites)
  const int nwg = gridDim.x;
  const int bid = blockIdx.x;
  const int swz = (bid & 7) * (nwg >> 3) + (bid >> 3);
  const int m0 = (swz / nbn) << 8, n0 = (swz % nbn) << 8;

  const int NT = K >> 6;

  const int srow = tid >> 3;                         // 0..63
  const int cg8  = ((tid & 7) ^ (srow & 7)) << 3;    // (row+64)&7 == row&7

  const unsigned short* gA = A  + (size_t)(m0 + srow) * K + cg8;
  const unsigned short* gB = Bt + (size_t)(n0 + srow) * K + cg8;
  const size_t rstep64  = (size_t)64 * K;
  const size_t rstep128 = (size_t)128 * K;

  // stage half-tile h of K-tile t: h = 0:A.h0  1:A.h1  2:B.h0  3:B.h1
  auto stage = [&](int t, int h) {
    const int buf = t & 1;
    const int k0 = t << 6;
    if (h < 2) {
      unsigned short* l = &As[buf][h][0] + tid * 8;
      const unsigned short* gp = gA + (size_t)h * rstep128 + k0;
      cp16(gp, l);
      cp16(gp + rstep64, l + 4096);
    } else {
      unsigned short* l = &Bs[buf][h - 2][0] + tid * 8;
      const unsigned short* gp = gB + (size_t)(h - 2) * rstep128 + k0;
      cp16(gp, l);
      cp16(gp + rstep64, l + 4096);
    }
  };

  const f32x4 fzero = {0.f, 0.f, 0.f, 0.f};
  f32x4 acc[8][4];
  #pragma unroll
  for (int i = 0; i < 8; i++)
    #pragma unroll
    for (int j = 0; j < 4; j++) acc[i][j] = fzero;

  // prologue: tile0 all 4 halves + tile1 B-halves (A-halves of tile1 staged
  // by tile0's P1/P2; B of tile t staged two tiles ahead in P3/P4).
  stage(0, 0); stage(0, 1); stage(0, 2); stage(0, 3);
  if (NT > 1) {
    stage(1, 2); stage(1, 3);
    asm volatile("s_waitcnt vmcnt(4)" ::: "memory");
  } else {
    asm volatile("s_waitcnt vmcnt(0)" ::: "memory");
  }
  asm volatile("s_barrier" ::: "memory");

  for (int t = 0; t < NT; ++t) {
    const int buf = t & 1;
    const unsigned short* cA = &As[buf][wm][0];
    const unsigned short* cB = &Bs[buf][bh][0];

    bf16x8 a0[4][2], a1[4][2], b0[2][2], b1[2][2];

    // ---- P1: read a0 (8) + b0 (4); stage t+1.A0; MFMA Q(0,0)
    #pragma unroll
    for (int i = 0; i < 4; i++)
      #pragma unroll
      for (int ks = 0; ks < 2; ks++)
        a0[i][ks] = *(const bf16x8*)&cA[(i*16 + c)*64 + ((((ks<<2)+q) ^ (c & 7)) << 3)];
    #pragma unroll
    for (int j = 0; j < 2; j++)
      #pragma unroll
      for (int ks = 0; ks < 2; ks++)
        b0[j][ks] = *(const bf16x8*)&cB[(bcol0 + j*16 + c)*64 + ((((ks<<2)+q) ^ (c & 7)) << 3)];
    if (t + 1 < NT) stage(t + 1, 0);
    asm volatile("s_barrier" ::: "memory");
    asm volatile("s_waitcnt lgkmcnt(0)" ::: "memory");
    __builtin_amdgcn_s_setprio(1);
    #pragma unroll
    for (int i = 0; i < 4; i++)
      #pragma unroll
      for (int j = 0; j < 2; j++)
        #pragma unroll
        for (int ks = 0; ks < 2; ks++)
          acc[i][j] = __builtin_amdgcn_mfma_f32_16x16x32_bf16(a0[i][ks], b0[j][ks], acc[i][j], 0, 0, 0);
    __builtin_amdgcn_s_setprio(0);
    asm volatile("s_barrier" ::: "memory");

    // ---- P2: read b1 (4); stage t+1.A1; MFMA Q(0,1); a0 dies here
    #pragma unroll
    for (int j = 0; j < 2; j++)
      #pragma unroll
      for (int ks = 0; ks < 2; ks++)
        b1[j][ks] = *(const bf16x8*)&cB[(bcol0 + (j+2)*16 + c)*64 + ((((ks<<2)+q) ^ (c & 7)) << 3)];
    if (t + 1 < NT) stage(t + 1, 1);
    asm volatile("s_barrier" ::: "memory");
    asm volatile("s_waitcnt lgkmcnt(0)" ::: "memory");
    __builtin_amdgcn_s_setprio(1);
    #pragma unroll
    for (int i = 0; i < 4; i++)
      #pragma unroll
      for (int j = 0; j < 2; j++)
        #pragma unroll
        for (int ks = 0; ks < 2; ks++)
          acc[i][j+2] = __builtin_amdgcn_mfma_f32_16x16x32_bf16(a0[i][ks], b1[j][ks], acc[i][j+2], 0, 0, 0);
    __builtin_amdgcn_s_setprio(0);
    asm volatile("s_barrier" ::: "memory");

    // ---- P3: read a1 (8); stage t+2.B0 into freed Bs[buf]; MFMA Q(1,1)
    #pragma unroll
    for (int i = 0; i < 4; i++)
      #pragma unroll
      for (int ks = 0; ks < 2; ks++)
        a1[i][ks] = *(const bf16x8*)&cA[((i+4)*16 + c)*64 + ((((ks<<2)+q) ^ (c & 7)) << 3)];
    if (t + 2 < NT) stage(t + 2, 2);
    asm volatile("s_barrier" ::: "memory");
    asm volatile("s_waitcnt lgkmcnt(0)" ::: "memory");
    __builtin_amdgcn_s_setprio(1);
    #pragma unroll
    for (int i = 0; i < 4; i++)
      #pragma unroll
      for (int j = 0; j < 2; j++)
        #pragma unroll
        for (int ks = 0; ks < 2; ks++)
          acc[i+4][j+2] = __builtin_amdgcn_mfma_f32_16x16x32_bf16(a1[i][ks], b1[j][ks], acc[i+4][j+2], 0, 0, 0);
    __builtin_amdgcn_s_setprio(0);
    asm volatile("s_barrier" ::: "memory");

    // ---- P4: no reads; stage t+2.B1; MFMA Q(1,0); counted vmcnt
    if (t + 2 < NT) stage(t + 2, 3);
    asm volatile("s_barrier" ::: "memory");
    __builtin_amdgcn_s_setprio(1);
    #pragma unroll
    for (int i = 0; i < 4; i++)
      #pragma unroll
      for (int j = 0; j < 2; j++)
        #pragma unroll
        for (int ks = 0; ks < 2; ks++)
          acc[i+4][j] = __builtin_amdgcn_mfma_f32_16x16x32_bf16(a1[i][ks], b0[j][ks], acc[i+4][j], 0, 0, 0);
    __builtin_amdgcn_s_setprio(0);
    if (t + 2 < NT)      asm volatile("s_waitcnt vmcnt(4)" ::: "memory");
    else if (t + 1 < NT) asm volatile("s_waitcnt vmcnt(0)" ::: "memory");
    if (t + 1 < NT) asm volatile("s_barrier" ::: "memory");
  }

  // epilogue
  float bj[4];
  #pragma unroll
  for (int j = 0; j < 4; j++) bj[j] = bias[n0 + wn * 64 + j * 16 + c];
  #pragma unroll
  for (int i = 0; i < 8; i++) {
    const int row = m0 + wm * 128 + i * 16 + q * 4;
    #pragma unroll
    for (int rr = 0; rr < 4; rr++) {
      unsigned short* orow = outp + (size_t)(row + rr) * N + n0 + wn * 64 + c;
      #pragma unroll
      for (int j = 0; j < 4; j++) {
        float v = acc[i][j][rr] + bj[j];
        if (MODE == 2) v = fmaxf(v, 0.f);
        orow[j * 16] = f2bf(v);
      }
    }
  }
}

// ---------------------------------------------------------------------------
// Flash attention, causal + rel_pos bias (round-5 proven version, verbatim).
// ---------------------------------------------------------------------------
__global__ __launch_bounds__(256, 2) void attn_flash(
    const unsigned short* __restrict__ qkv,   // [4096, 3072] bf16 (q|k|v)
    const float* __restrict__ rel_pos,        // [16, 2048] fp32
    unsigned short* __restrict__ o) {         // [4096, 1024] bf16 ([b,s,h,d])
  __shared__ __align__(16) unsigned short Qs[128 * 64];
  __shared__ __align__(16) unsigned short Ks[64 * 64];
  __shared__ __align__(16) unsigned short Vs[64 * 64];   // transposed [d][kt]
  __shared__ __align__(16) unsigned short Ps[4][32 * 64];
  __shared__ float rps[1024];                            // rel_pos[h,:]*log2e

  const int tid = threadIdx.x;
  const int wave = tid >> 6, lane = tid & 63;
  const int q = lane >> 4, c = lane & 15;

  const int lid = blockIdx.x + (blockIdx.y << 3);
  const int xq = lid & 7, y = lid >> 3;
  const int qt = (y & 32) ? (7 - xq) : xq;
  const int b = y >> 4, h = y & 15;

  const unsigned short* qg = qkv + (size_t)b * 1024 * 3072 + h * 64;
  const unsigned short* kg = qg + 1024;
  const unsigned short* vg = qg + 2048;

  #pragma unroll
  for (int i = 0; i < 4; i++) {
    const int idx = tid + i * 256;
    rps[idx & 1023] = rel_pos[h * 2048 + (idx & 1023)] * 1.44269504f;
  }

  const int sr  = tid >> 3;
  const int cg8 = ((tid & 7) ^ (sr & 7)) << 3;
  #pragma unroll
  for (int it = 0; it < 4; it++)
    cp16(qg + (size_t)(qt * 128 + sr + it * 32) * 3072 + cg8, &Qs[(tid + it * 256) * 8]);
  __syncthreads();

  bf16x8 qf[2][2];
  #pragma unroll
  for (int mt = 0; mt < 2; mt++)
    #pragma unroll
    for (int ks = 0; ks < 2; ks++)
      qf[mt][ks] = *(const bf16x8*)&Qs[(wave*32 + mt*16 + c)*64 + ((((ks<<2)+q) ^ (c & 7)) << 3)];

  const f32x4 fzero = {0.f, 0.f, 0.f, 0.f};
  f32x4 O[2][4];
  float l_i[2][4];
  #pragma unroll
  for (int mt = 0; mt < 2; mt++) {
    #pragma unroll
    for (int r = 0; r < 4; r++) l_i[mt][r] = 0.f;
    #pragma unroll
    for (int dt = 0; dt < 4; dt++) O[mt][dt] = fzero;
  }

  unsigned short* Pw = &Ps[wave][0];
  const int i_base = qt * 128 + wave * 32;
  const int vrow = tid & 63, d0 = (tid >> 6) << 4;
  const int vchunk = vrow >> 3, vlo = vrow & 7;

  const float sc = 0.125f * 1.44269504f;
  const int kdiag = qt << 1;
  const int nkt = (qt + 1) * 2;

  for (int kt = 0; kt < nkt; kt++) {
    __syncthreads();
    cp16(kg + (size_t)(kt * 64 + sr) * 3072 + cg8, &Ks[tid * 8]);
    cp16(kg + (size_t)(kt * 64 + sr + 32) * 3072 + cg8, &Ks[(tid + 256) * 8]);
    {
      union { int4 v; unsigned short u[8]; } va, vb2;
      const unsigned short* vrp = vg + (size_t)(kt * 64 + vrow) * 3072 + d0;
      va.v  = *(const int4*)vrp;
      vb2.v = *(const int4*)(vrp + 8);
      #pragma unroll
      for (int j = 0; j < 8; j++) {
        const int pos = ((vchunk ^ j) << 3) + vlo;
        Vs[(d0 + j) * 64 + pos]     = va.u[j];
        Vs[(d0 + 8 + j) * 64 + pos] = vb2.u[j];
      }
    }
    __syncthreads();

    f32x4 S[2][4];
    #pragma unroll
    for (int mt = 0; mt < 2; mt++)
      #pragma unroll
      for (int nt = 0; nt < 4; nt++) S[mt][nt] = fzero;
    #pragma unroll
    for (int ks = 0; ks < 2; ks++) {
      const int sw = (((ks << 2) + q) ^ (c & 7)) << 3;
      bf16x8 kb[4];
      #pragma unroll
      for (int nt = 0; nt < 4; nt++) kb[nt] = *(const bf16x8*)&Ks[(nt*16 + c)*64 + sw];
      #pragma unroll
      for (int mt = 0; mt < 2; mt++)
        #pragma unroll
        for (int nt = 0; nt < 4; nt++)
          S[mt][nt] = __builtin_amdgcn_mfma_f32_16x16x32_bf16(qf[mt][ks], kb[nt], S[mt][nt], 0, 0, 0);
    }

    if (kt < kdiag) {
      #pragma unroll
      for (int mt = 0; mt < 2; mt++) {
        #pragma unroll
        for (int r = 0; r < 4; r++) {
          const int i_ = i_base + mt * 16 + q * 4 + r;
          const int prow = (mt * 16 + q * 4 + r) * 64;
          const int rsw  = (q * 4 + r) & 7;
          float s = 0.f;
          #pragma unroll
          for (int nt = 0; nt < 4; nt++) {
            const int j_ = kt * 64 + nt * 16 + c;
            const float p = exp2f(fmaf(S[mt][nt][r], sc, rps[i_ - j_]));
            s += p;
            Pw[prow + ((((nt << 1) + (c >> 3)) ^ rsw) << 3) + (c & 7)] = f2bf_fast(p);
          }
          l_i[mt][r] += s;
        }
      }
    } else {
      #pragma unroll
      for (int mt = 0; mt < 2; mt++) {
        #pragma unroll
        for (int r = 0; r < 4; r++) {
          const int i_ = i_base + mt * 16 + q * 4 + r;
          const int prow = (mt * 16 + q * 4 + r) * 64;
          const int rsw  = (q * 4 + r) & 7;
          float s = 0.f;
          #pragma unroll
          for (int nt = 0; nt < 4; nt++) {
            const int j_ = kt * 64 + nt * 16 + c;
            const int d_ = i_ - j_;
            const float p = (d_ >= 0)
                ? exp2f(fmaf(S[mt][nt][r], sc, rps[d_ & 1023])) : 0.f;
            s += p;
            Pw[prow + ((((nt << 1) + (c >> 3)) ^ rsw) << 3) + (c & 7)] = f2bf_fast(p);
          }
          l_i[mt][r] += s;
        }
      }
    }

    asm volatile("s_waitcnt lgkmcnt(0)" ::: "memory");

    #pragma unroll
    for (int ks = 0; ks < 2; ks++) {
      const int sw = (((ks << 2) + q) ^ (c & 7)) << 3;
      bf16x8 pa[2], vb[4];
      #pragma unroll
      for (int mt = 0; mt < 2; mt++) pa[mt] = *(const bf16x8*)&Pw[(mt*16 + c)*64 + sw];
      #pragma unroll
      for (int dt = 0; dt < 4; dt++) vb[dt] = *(const bf16x8*)&Vs[(dt*16 + c)*64 + sw];
      #pragma unroll
      for (int mt = 0; mt < 2; mt++)
        #pragma unroll
        for (int dt = 0; dt < 4; dt++)
          O[mt][dt] = __builtin_amdgcn_mfma_f32_16x16x32_bf16(pa[mt], vb[dt], O[mt][dt], 0, 0, 0);
    }
  }

  #pragma unroll
  for (int mt = 0; mt < 2; mt++) {
    #pragma unroll
    for (int r = 0; r < 4; r++) {
      float l = l_i[mt][r];
      l += __shfl_xor(l, 1, 64);
      l += __shfl_xor(l, 2, 64);
      l += __shfl_xor(l, 4, 64);
      l += __shfl_xor(l, 8, 64);
      const float inv = 1.0f / l;
      const int i_ = i_base + mt * 16 + q * 4 + r;
      unsigned short* orow = o + (size_t)(b * 1024 + i_) * 1024 + h * 64 + c;
      #pragma unroll
      for (int dt = 0; dt < 4; dt++) orow[dt * 16] = f2bf(O[mt][dt][r] * inv);
    }
  }
}

// ---------------------------------------------------------------------------
// Launch. Workspace aliased down to ~81 MB (less 0xAA re-poison traffic):
//   xm == xn (xn dead after QKV); hb == qkvb|ob (both dead after out-proj).
// ---------------------------------------------------------------------------
extern "C" void kernel_launch(void* const* d_in, const int* in_sizes, int n_in,
                              void* d_out, int out_size, void* d_ws, size_t ws_size,
                              hipStream_t stream) {
  (void)in_sizes; (void)n_in; (void)out_size; (void)ws_size;
  const float* x    = (const float*)d_in[0];
  const float* rel  = (const float*)d_in[1];
  const float* ipw  = (const float*)d_in[2];
  const float* ipb  = (const float*)d_in[3];
  const float* outw = (const float*)d_in[4];
  const float* outb = (const float*)d_in[5];
  const float* w1   = (const float*)d_in[6];
  const float* b1   = (const float*)d_in[7];
  const float* w2   = (const float*)d_in[8];
  const float* b2   = (const float*)d_in[9];
  const float* ln1g = (const float*)d_in[10];
  const float* ln1b = (const float*)d_in[11];
  const float* ln2g = (const float*)d_in[12];
  const float* ln2b = (const float*)d_in[13];

  // workspace layout (elements), aliased:
  unsigned short* ipw_b  = (unsigned short*)d_ws;            // 3072*1024
  unsigned short* outw_b = ipw_b  + (size_t)3072 * 1024;     // 1024*1024
  unsigned short* w1_b   = outw_b + (size_t)1024 * 1024;     // 4096*1024
  unsigned short* w2_b   = w1_b   + (size_t)4096 * 1024;     // 1024*4096
  unsigned short* xn     = w2_b   + (size_t)1024 * 4096;     // 4096*1024 (also xm)
  unsigned short* qkvb   = xn     + (size_t)4096 * 1024;     // 4096*3072 ┐
  unsigned short* ob     = qkvb   + (size_t)4096 * 3072;     // 4096*1024 ┴ hb aliases both
  unsigned short* hb     = qkvb;                             // 4096*4096 (after out-proj)
  unsigned short* xm     = xn;                               // after QKV consumed xn
  float*          x2     = (float*)(ob + (size_t)4096 * 1024);  // 4096*1024 f32
  // total = 81 MB

  // fused: weight converts + ln1 + seed x2 = x + outb
  cvt_ln1<<<16384, 256, 0, stream>>>(ipw, outw, w1, w2, ipw_b, outw_b, w1_b, w2_b,
                                     x, ln1g, ln1b, xn, outb, x2);

  // QKV proj: 256^2-tile 8-phase v2, grid 16x12 = 192 blocks
  gemm256<0><<<192, 512, 0, stream>>>(xn, ipw_b, ipb, qkvb, 3072, 1024, 12);

  attn_flash<<<dim3(8, 64), 256, 0, stream>>>(qkvb, rel, ob);

  // attn out proj: x2 += ob @ outw^T  (split-K=2, atomic)
  gemm_bt_splitk<<<dim3(32, 8, 2), 256, 0, stream>>>(ob, outw_b, x2, 1024, 1024);

  // ln2 + seed d_out = x2 + b2
  ln_bf16_seed<<<4096, 256, 0, stream>>>(x2, ln2g, ln2b, xm, b2, (float*)d_out);

  // MLP up: 256^2-tile 8-phase v2, grid 16x16 = 256 blocks (1 block/CU)
  gemm256<2><<<256, 512, 0, stream>>>(xm, w1_b, b1, hb, 4096, 1024, 16);

  // MLP down: d_out += hb @ w2^T  (split-K=2, atomic)
  gemm_bt_splitk<<<dim3(32, 8, 2), 256, 0, stream>>>(hb, w2_b, (float*)d_out, 1024, 4096);
}

// Round 4
// 334.300 us; speedup vs baseline: 1.0189x; 1.0189x over previous
//
#include <hip/hip_runtime.h>
#include <stdint.h>

// ---------------------------------------------------------------------------
// Types / helpers
// ---------------------------------------------------------------------------
typedef __bf16 bf16x8 __attribute__((ext_vector_type(8)));
typedef float  f32x4  __attribute__((ext_vector_type(4)));

__device__ __forceinline__ unsigned short f2bf(float f) {
  union { float f; unsigned int u; } a; a.f = f;
  unsigned int r = a.u + 0x7FFFu + ((a.u >> 16) & 1u);   // RNE
  return (unsigned short)(r >> 16);
}

__device__ __forceinline__ unsigned short f2bf_fast(float f) {
  union { __bf16 b; unsigned short u; } v; v.b = (__bf16)f; return v.u;
}

// async global->LDS, 16B per lane. LDS dest must be wave-uniform base + lane*16.
__device__ __forceinline__ void cp16(const void* g, void* l) {
  auto g1 = reinterpret_cast<__attribute__((address_space(1))) unsigned int*>(
      reinterpret_cast<uintptr_t>(g));
  auto l3 = reinterpret_cast<__attribute__((address_space(3))) unsigned int*>(
      reinterpret_cast<uintptr_t>(l));
  __builtin_amdgcn_global_load_lds(g1, l3, 16, 0, 0);
}

// ---------------------------------------------------------------------------
// Fused: weight fp32->bf16 convert (blocks 0..12287) AND ln1+seed (blocks
// 12288..16383). Independent work, one launch to cut a kernel gap.
// ---------------------------------------------------------------------------
__global__ __launch_bounds__(256) void cvt_ln1(
    const float* __restrict__ s0, const float* __restrict__ s1,
    const float* __restrict__ s2, const float* __restrict__ s3,
    unsigned short* __restrict__ d0, unsigned short* __restrict__ d1,
    unsigned short* __restrict__ d2, unsigned short* __restrict__ d3,
    const float* __restrict__ x,
    const float* __restrict__ g,
    const float* __restrict__ bta,
    unsigned short* __restrict__ out,
    const float* __restrict__ seed_bias,
    float* __restrict__ seed_out) {
  if (blockIdx.x < 12288) {
    int i = (blockIdx.x * 256 + threadIdx.x) * 4;
    const float* src; unsigned short* dst; int off;
    if (i < 3145728)       { src = s0; dst = d0; off = 0; }
    else if (i < 4194304)  { src = s1; dst = d1; off = 3145728; }
    else if (i < 8388608)  { src = s2; dst = d2; off = 4194304; }
    else                   { src = s3; dst = d3; off = 8388608; }
    i -= off;
    float4 v = *(const float4*)(src + i);
    union { unsigned short u[4]; uint2 p; } o;
    o.u[0] = f2bf(v.x); o.u[1] = f2bf(v.y); o.u[2] = f2bf(v.z); o.u[3] = f2bf(v.w);
    *(uint2*)(dst + i) = o.p;
    return;
  }
  const int row = blockIdx.x - 12288, t = threadIdx.x;
  const float4 v = *(const float4*)(x + (size_t)row * 1024 + t * 4);
  {
    float4 sb = *(const float4*)(seed_bias + t * 4);
    float4 sv;
    sv.x = v.x + sb.x; sv.y = v.y + sb.y; sv.z = v.z + sb.z; sv.w = v.w + sb.w;
    *(float4*)(seed_out + (size_t)row * 1024 + t * 4) = sv;
  }
  float s1v = v.x + v.y + v.z + v.w;
  float s2v = v.x*v.x + v.y*v.y + v.z*v.z + v.w*v.w;
  #pragma unroll
  for (int off = 1; off < 64; off <<= 1) {
    s1v += __shfl_xor(s1v, off, 64);
    s2v += __shfl_xor(s2v, off, 64);
  }
  __shared__ float r1[4], r2[4];
  if ((t & 63) == 0) { r1[t >> 6] = s1v; r2[t >> 6] = s2v; }
  __syncthreads();
  s1v = r1[0] + r1[1] + r1[2] + r1[3];
  s2v = r2[0] + r2[1] + r2[2] + r2[3];
  const float mean = s1v * (1.0f / 1024.0f);
  const float var  = s2v * (1.0f / 1024.0f) - mean * mean;
  const float rstd = rsqrtf(var + 1e-5f);
  const float4 gv = *(const float4*)(g + t * 4);
  const float4 bv = *(const float4*)(bta + t * 4);
  union { unsigned short u[4]; uint2 p; } o;
  o.u[0] = f2bf((v.x - mean) * rstd * gv.x + bv.x);
  o.u[1] = f2bf((v.y - mean) * rstd * gv.y + bv.y);
  o.u[2] = f2bf((v.z - mean) * rstd * gv.z + bv.z);
  o.u[3] = f2bf((v.w - mean) * rstd * gv.w + bv.w);
  *(uint2*)(out + (size_t)row * 1024 + t * 4) = o.p;
}

// ---------------------------------------------------------------------------
// LayerNorm (E=1024), fp32 in -> bf16 out, PLUS seeds the next split-K GEMM's
// accumulator: seed_out[row,:] = x[row,:] + seed_bias[:].
// ---------------------------------------------------------------------------
__global__ __launch_bounds__(256) void ln_bf16_seed(
    const float* __restrict__ x,
    const float* __restrict__ g,
    const float* __restrict__ bta,
    unsigned short* __restrict__ out,
    const float* __restrict__ seed_bias,
    float* __restrict__ seed_out) {
  const int row = blockIdx.x, t = threadIdx.x;
  const float4 v = *(const float4*)(x + (size_t)row * 1024 + t * 4);
  {
    float4 sb = *(const float4*)(seed_bias + t * 4);
    float4 sv;
    sv.x = v.x + sb.x; sv.y = v.y + sb.y; sv.z = v.z + sb.z; sv.w = v.w + sb.w;
    *(float4*)(seed_out + (size_t)row * 1024 + t * 4) = sv;
  }
  float s1 = v.x + v.y + v.z + v.w;
  float s2 = v.x*v.x + v.y*v.y + v.z*v.z + v.w*v.w;
  #pragma unroll
  for (int off = 1; off < 64; off <<= 1) {
    s1 += __shfl_xor(s1, off, 64);
    s2 += __shfl_xor(s2, off, 64);
  }
  __shared__ float r1[4], r2[4];
  if ((t & 63) == 0) { r1[t >> 6] = s1; r2[t >> 6] = s2; }
  __syncthreads();
  s1 = r1[0] + r1[1] + r1[2] + r1[3];
  s2 = r2[0] + r2[1] + r2[2] + r2[3];
  const float mean = s1 * (1.0f / 1024.0f);
  const float var  = s2 * (1.0f / 1024.0f) - mean * mean;
  const float rstd = rsqrtf(var + 1e-5f);
  const float4 gv = *(const float4*)(g + t * 4);
  const float4 bv = *(const float4*)(bta + t * 4);
  union { unsigned short u[4]; uint2 p; } o;
  o.u[0] = f2bf((v.x - mean) * rstd * gv.x + bv.x);
  o.u[1] = f2bf((v.y - mean) * rstd * gv.y + bv.y);
  o.u[2] = f2bf((v.z - mean) * rstd * gv.z + bv.z);
  o.u[3] = f2bf((v.w - mean) * rstd * gv.w + bv.w);
  *(uint2*)(out + (size_t)row * 1024 + t * 4) = o.p;
}

// ---------------------------------------------------------------------------
// Pipelined GEMM core. R5 2-barrier skeleton, now with A TRIPLE-buffered
// (prefetch distance 3 K-steps) and B double-buffered (distance 2).
// Rationale: MfmaUtil 23% / Occ 16% / HBM 19% on splitk => latency-bound;
// step time T >= load_latency/distance. A operands (activations, fresh
// writes) have L3/HBM latency ~450-900 cyc; distance 2 * ~300cyc compute
// did not cover it. Distance 3 for A targets T ~= compute.
// vmcnt: at step t's top, in-flight newer than B(t) = {A(t+1),B(t+1),A(t+2)}
// = 12 (tails: 8 / 0). End-of-step issues (after barrier) target exactly the
// buffers freed this step: B(t+2)->bufB t%2, A(t+3)->bufA t%3.
// LDS: 3*16K(A) + 2*16K(B) = 80KB/block, 2 blocks/CU = 160KB exact.
// MODE 0 = bf16 v+bias; MODE 2 = bf16 relu(v+bias); MODE 4 = atomic fp32 +=v.
// ---------------------------------------------------------------------------
template <int MODE>
__device__ __forceinline__ void gemm_core(
    const unsigned short* __restrict__ A,
    const unsigned short* __restrict__ Bt,
    const float* __restrict__ bias,
    void* __restrict__ outp,
    int N, int K, int kbeg, int kend,
    unsigned short* As, unsigned short* Bs) {   // As [3][8192], Bs [2][8192]
  const int tid = threadIdx.x;
  const int wave = tid >> 6, lane = tid & 63;
  const int q = lane >> 4, c = lane & 15;
  const int wm = (wave & 1) << 6, wn = (wave >> 1) << 6;
  const int m0 = blockIdx.x << 7, n0 = blockIdx.y << 7;

  const int srow = tid >> 3;                       // 0..31
  const int cg8  = ((tid & 7) ^ (srow & 7)) << 3;  // swizzled col chunk

  const unsigned short* gA = A  + (size_t)(m0 + srow) * K + cg8;
  const unsigned short* gB = Bt + (size_t)(n0 + srow) * K + cg8;
  const size_t rstep = (size_t)32 * K;

  auto issueA = [&](int k0, int buf) {
    unsigned short* lA = As + buf * 8192 + tid * 8;
    #pragma unroll
    for (int it = 0; it < 4; it++) cp16(gA + it * rstep + k0, lA + it * 2048);
  };
  auto issueB = [&](int k0, int buf) {
    unsigned short* lB = Bs + buf * 8192 + tid * 8;
    #pragma unroll
    for (int it = 0; it < 4; it++) cp16(gB + it * rstep + k0, lB + it * 2048);
  };

  const f32x4 fzero = {0.f, 0.f, 0.f, 0.f};
  f32x4 acc[4][4];
  #pragma unroll
  for (int i = 0; i < 4; i++)
    #pragma unroll
    for (int j = 0; j < 4; j++) acc[i][j] = fzero;

  const int NT = (kend - kbeg) >> 6;

  // prologue: A0 B0 A1 B1 A2  (oldest -> newest)
  issueA(kbeg, 0); issueB(kbeg, 0);
  if (NT > 1) { issueA(kbeg + 64, 1); issueB(kbeg + 64, 1); }
  if (NT > 2) issueA(kbeg + 128, 2);

  int ba = 0, bb = 0;
  for (int t = 0; t < NT; ++t) {
    if (t + 2 < NT)      asm volatile("s_waitcnt vmcnt(12)" ::: "memory");
    else if (t + 1 < NT) asm volatile("s_waitcnt vmcnt(8)" ::: "memory");
    else                 asm volatile("s_waitcnt vmcnt(0)" ::: "memory");
    asm volatile("s_barrier" ::: "memory");

    const unsigned short* cA = As + ba * 8192;
    const unsigned short* cB = Bs + bb * 8192;
    #pragma unroll
    for (int ks = 0; ks < 2; ks++) {
      const int sw = (((ks << 2) + q) ^ (c & 7)) << 3;
      bf16x8 af[4], bf[4];
      #pragma unroll
      for (int i = 0; i < 4; i++) af[i] = *(const bf16x8*)&cA[(wm + i*16 + c)*64 + sw];
      #pragma unroll
      for (int j = 0; j < 4; j++) bf[j] = *(const bf16x8*)&cB[(wn + j*16 + c)*64 + sw];
      #pragma unroll
      for (int i = 0; i < 4; i++)
        #pragma unroll
        for (int j = 0; j < 4; j++)
          acc[i][j] = __builtin_amdgcn_mfma_f32_16x16x32_bf16(af[i], bf[j], acc[i][j], 0, 0, 0);
    }

    asm volatile("s_barrier" ::: "memory");
    if (t + 2 < NT) issueB(kbeg + (t + 2) * 64, bb);   // bufB (t+2)%2 == t%2, just freed
    if (t + 3 < NT) issueA(kbeg + (t + 3) * 64, ba);   // bufA (t+3)%3 == t%3, just freed
    ba = (ba == 2) ? 0 : ba + 1;
    bb ^= 1;
  }

  if (MODE == 4) {
    float* op = (float*)outp;
    #pragma unroll
    for (int i = 0; i < 4; i++) {
      #pragma unroll
      for (int r = 0; r < 4; r++) {
        const int row = m0 + wm + i * 16 + q * 4 + r;
        #pragma unroll
        for (int j = 0; j < 4; j++) {
          const int col = n0 + wn + j * 16 + c;
          atomicAdd(op + (size_t)row * N + col, acc[i][j][r]);
        }
      }
    }
  } else {
    float bj[4];
    #pragma unroll
    for (int j = 0; j < 4; j++) bj[j] = bias[n0 + wn + j * 16 + c];
    #pragma unroll
    for (int i = 0; i < 4; i++) {
      #pragma unroll
      for (int r = 0; r < 4; r++) {
        const int row = m0 + wm + i * 16 + q * 4 + r;
        #pragma unroll
        for (int j = 0; j < 4; j++) {
          const int col = n0 + wn + j * 16 + c;
          const size_t idx = (size_t)row * N + col;
          float v = acc[i][j][r] + bj[j];
          if (MODE == 0) ((unsigned short*)outp)[idx] = f2bf(v);
          else           ((unsigned short*)outp)[idx] = f2bf(fmaxf(v, 0.f));
        }
      }
    }
  }
}

template <int MODE>
__global__ __launch_bounds__(256, 2) void gemm_bt(
    const unsigned short* __restrict__ A,
    const unsigned short* __restrict__ Bt,
    const float* __restrict__ bias,
    void* __restrict__ outp,
    int N, int K) {
  __shared__ __align__(16) unsigned short As[3 * 8192];
  __shared__ __align__(16) unsigned short Bs[2 * 8192];
  gemm_core<MODE>(A, Bt, bias, outp, N, K, 0, K, As, Bs);
}

// split-K=2: z in {0,1}, atomicAdd into pre-seeded fp32 output
__global__ __launch_bounds__(256, 2) void gemm_bt_splitk(
    const unsigned short* __restrict__ A,
    const unsigned short* __restrict__ Bt,
    float* __restrict__ outp,
    int N, int K) {
  __shared__ __align__(16) unsigned short As[3 * 8192];
  __shared__ __align__(16) unsigned short Bs[2 * 8192];
  const int KH = K >> 1;
  const int kbeg = blockIdx.z * KH;
  gemm_core<4>(A, Bt, nullptr, outp, N, K, kbeg, kbeg + KH, As, Bs);
}

// ---------------------------------------------------------------------------
// Flash attention, causal + rel_pos bias (round-5 proven version, verbatim).
// ---------------------------------------------------------------------------
__global__ __launch_bounds__(256, 2) void attn_flash(
    const unsigned short* __restrict__ qkv,   // [4096, 3072] bf16 (q|k|v)
    const float* __restrict__ rel_pos,        // [16, 2048] fp32
    unsigned short* __restrict__ o) {         // [4096, 1024] bf16 ([b,s,h,d])
  __shared__ __align__(16) unsigned short Qs[128 * 64];
  __shared__ __align__(16) unsigned short Ks[64 * 64];
  __shared__ __align__(16) unsigned short Vs[64 * 64];   // transposed [d][kt]
  __shared__ __align__(16) unsigned short Ps[4][32 * 64];
  __shared__ float rps[1024];                            // rel_pos[h,:]*log2e

  const int tid = threadIdx.x;
  const int wave = tid >> 6, lane = tid & 63;
  const int q = lane >> 4, c = lane & 15;

  const int lid = blockIdx.x + (blockIdx.y << 3);
  const int xq = lid & 7, y = lid >> 3;
  const int qt = (y & 32) ? (7 - xq) : xq;
  const int b = y >> 4, h = y & 15;

  const unsigned short* qg = qkv + (size_t)b * 1024 * 3072 + h * 64;
  const unsigned short* kg = qg + 1024;
  const unsigned short* vg = qg + 2048;

  #pragma unroll
  for (int i = 0; i < 4; i++) {
    const int idx = tid + i * 256;
    rps[idx & 1023] = rel_pos[h * 2048 + (idx & 1023)] * 1.44269504f;
  }

  const int sr  = tid >> 3;
  const int cg8 = ((tid & 7) ^ (sr & 7)) << 3;
  #pragma unroll
  for (int it = 0; it < 4; it++)
    cp16(qg + (size_t)(qt * 128 + sr + it * 32) * 3072 + cg8, &Qs[(tid + it * 256) * 8]);
  __syncthreads();

  bf16x8 qf[2][2];
  #pragma unroll
  for (int mt = 0; mt < 2; mt++)
    #pragma unroll
    for (int ks = 0; ks < 2; ks++)
      qf[mt][ks] = *(const bf16x8*)&Qs[(wave*32 + mt*16 + c)*64 + ((((ks<<2)+q) ^ (c & 7)) << 3)];

  const f32x4 fzero = {0.f, 0.f, 0.f, 0.f};
  f32x4 O[2][4];
  float l_i[2][4];
  #pragma unroll
  for (int mt = 0; mt < 2; mt++) {
    #pragma unroll
    for (int r = 0; r < 4; r++) l_i[mt][r] = 0.f;
    #pragma unroll
    for (int dt = 0; dt < 4; dt++) O[mt][dt] = fzero;
  }

  unsigned short* Pw = &Ps[wave][0];
  const int i_base = qt * 128 + wave * 32;
  const int vrow = tid & 63, d0 = (tid >> 6) << 4;
  const int vchunk = vrow >> 3, vlo = vrow & 7;

  const float sc = 0.125f * 1.44269504f;
  const int kdiag = qt << 1;
  const int nkt = (qt + 1) * 2;

  for (int kt = 0; kt < nkt; kt++) {
    __syncthreads();
    cp16(kg + (size_t)(kt * 64 + sr) * 3072 + cg8, &Ks[tid * 8]);
    cp16(kg + (size_t)(kt * 64 + sr + 32) * 3072 + cg8, &Ks[(tid + 256) * 8]);
    {
      union { int4 v; unsigned short u[8]; } va, vb2;
      const unsigned short* vrp = vg + (size_t)(kt * 64 + vrow) * 3072 + d0;
      va.v  = *(const int4*)vrp;
      vb2.v = *(const int4*)(vrp + 8);
      #pragma unroll
      for (int j = 0; j < 8; j++) {
        const int pos = ((vchunk ^ j) << 3) + vlo;
        Vs[(d0 + j) * 64 + pos]     = va.u[j];
        Vs[(d0 + 8 + j) * 64 + pos] = vb2.u[j];
      }
    }
    __syncthreads();

    f32x4 S[2][4];
    #pragma unroll
    for (int mt = 0; mt < 2; mt++)
      #pragma unroll
      for (int nt = 0; nt < 4; nt++) S[mt][nt] = fzero;
    #pragma unroll
    for (int ks = 0; ks < 2; ks++) {
      const int sw = (((ks << 2) + q) ^ (c & 7)) << 3;
      bf16x8 kb[4];
      #pragma unroll
      for (int nt = 0; nt < 4; nt++) kb[nt] = *(const bf16x8*)&Ks[(nt*16 + c)*64 + sw];
      #pragma unroll
      for (int mt = 0; mt < 2; mt++)
        #pragma unroll
        for (int nt = 0; nt < 4; nt++)
          S[mt][nt] = __builtin_amdgcn_mfma_f32_16x16x32_bf16(qf[mt][ks], kb[nt], S[mt][nt], 0, 0, 0);
    }

    if (kt < kdiag) {
      #pragma unroll
      for (int mt = 0; mt < 2; mt++) {
        #pragma unroll
        for (int r = 0; r < 4; r++) {
          const int i_ = i_base + mt * 16 + q * 4 + r;
          const int prow = (mt * 16 + q * 4 + r) * 64;
          const int rsw  = (q * 4 + r) & 7;
          float s = 0.f;
          #pragma unroll
          for (int nt = 0; nt < 4; nt++) {
            const int j_ = kt * 64 + nt * 16 + c;
            const float p = exp2f(fmaf(S[mt][nt][r], sc, rps[i_ - j_]));
            s += p;
            Pw[prow + ((((nt << 1) + (c >> 3)) ^ rsw) << 3) + (c & 7)] = f2bf_fast(p);
          }
          l_i[mt][r] += s;
        }
      }
    } else {
      #pragma unroll
      for (int mt = 0; mt < 2; mt++) {
        #pragma unroll
        for (int r = 0; r < 4; r++) {
          const int i_ = i_base + mt * 16 + q * 4 + r;
          const int prow = (mt * 16 + q * 4 + r) * 64;
          const int rsw  = (q * 4 + r) & 7;
          float s = 0.f;
          #pragma unroll
          for (int nt = 0; nt < 4; nt++) {
            const int j_ = kt * 64 + nt * 16 + c;
            const int d_ = i_ - j_;
            const float p = (d_ >= 0)
                ? exp2f(fmaf(S[mt][nt][r], sc, rps[d_ & 1023])) : 0.f;
            s += p;
            Pw[prow + ((((nt << 1) + (c >> 3)) ^ rsw) << 3) + (c & 7)] = f2bf_fast(p);
          }
          l_i[mt][r] += s;
        }
      }
    }

    asm volatile("s_waitcnt lgkmcnt(0)" ::: "memory");

    #pragma unroll
    for (int ks = 0; ks < 2; ks++) {
      const int sw = (((ks << 2) + q) ^ (c & 7)) << 3;
      bf16x8 pa[2], vb[4];
      #pragma unroll
      for (int mt = 0; mt < 2; mt++) pa[mt] = *(const bf16x8*)&Pw[(mt*16 + c)*64 + sw];
      #pragma unroll
      for (int dt = 0; dt < 4; dt++) vb[dt] = *(const bf16x8*)&Vs[(dt*16 + c)*64 + sw];
      #pragma unroll
      for (int mt = 0; mt < 2; mt++)
        #pragma unroll
        for (int dt = 0; dt < 4; dt++)
          O[mt][dt] = __builtin_amdgcn_mfma_f32_16x16x32_bf16(pa[mt], vb[dt], O[mt][dt], 0, 0, 0);
    }
  }

  #pragma unroll
  for (int mt = 0; mt < 2; mt++) {
    #pragma unroll
    for (int r = 0; r < 4; r++) {
      float l = l_i[mt][r];
      l += __shfl_xor(l, 1, 64);
      l += __shfl_xor(l, 2, 64);
      l += __shfl_xor(l, 4, 64);
      l += __shfl_xor(l, 8, 64);
      const float inv = 1.0f / l;
      const int i_ = i_base + mt * 16 + q * 4 + r;
      unsigned short* orow = o + (size_t)(b * 1024 + i_) * 1024 + h * 64 + c;
      #pragma unroll
      for (int dt = 0; dt < 4; dt++) orow[dt * 16] = f2bf(O[mt][dt][r] * inv);
    }
  }
}

// ---------------------------------------------------------------------------
// Launch. Workspace aliased down to ~81 MB (less 0xAA re-poison traffic):
//   xm == xn (xn dead after QKV); hb == qkvb|ob (both dead after out-proj).
// ---------------------------------------------------------------------------
extern "C" void kernel_launch(void* const* d_in, const int* in_sizes, int n_in,
                              void* d_out, int out_size, void* d_ws, size_t ws_size,
                              hipStream_t stream) {
  (void)in_sizes; (void)n_in; (void)out_size; (void)ws_size;
  const float* x    = (const float*)d_in[0];
  const float* rel  = (const float*)d_in[1];
  const float* ipw  = (const float*)d_in[2];
  const float* ipb  = (const float*)d_in[3];
  const float* outw = (const float*)d_in[4];
  const float* outb = (const float*)d_in[5];
  const float* w1   = (const float*)d_in[6];
  const float* b1   = (const float*)d_in[7];
  const float* w2   = (const float*)d_in[8];
  const float* b2   = (const float*)d_in[9];
  const float* ln1g = (const float*)d_in[10];
  const float* ln1b = (const float*)d_in[11];
  const float* ln2g = (const float*)d_in[12];
  const float* ln2b = (const float*)d_in[13];

  // workspace layout (elements), aliased:
  unsigned short* ipw_b  = (unsigned short*)d_ws;            // 3072*1024
  unsigned short* outw_b = ipw_b  + (size_t)3072 * 1024;     // 1024*1024
  unsigned short* w1_b   = outw_b + (size_t)1024 * 1024;     // 4096*1024
  unsigned short* w2_b   = w1_b   + (size_t)4096 * 1024;     // 1024*4096
  unsigned short* xn     = w2_b   + (size_t)1024 * 4096;     // 4096*1024 (also xm)
  unsigned short* qkvb   = xn     + (size_t)4096 * 1024;     // 4096*3072 ┐
  unsigned short* ob     = qkvb   + (size_t)4096 * 3072;     // 4096*1024 ┴ hb aliases both
  unsigned short* hb     = qkvb;                             // 4096*4096 (after out-proj)
  unsigned short* xm     = xn;                               // after QKV consumed xn
  float*          x2     = (float*)(ob + (size_t)4096 * 1024);  // 4096*1024 f32
  // total = 81 MB

  // fused: weight converts + ln1 + seed x2 = x + outb
  cvt_ln1<<<16384, 256, 0, stream>>>(ipw, outw, w1, w2, ipw_b, outw_b, w1_b, w2_b,
                                     x, ln1g, ln1b, xn, outb, x2);

  // QKV proj
  gemm_bt<0><<<dim3(32, 24), 256, 0, stream>>>(xn, ipw_b, ipb, qkvb, 3072, 1024);

  attn_flash<<<dim3(8, 64), 256, 0, stream>>>(qkvb, rel, ob);

  // attn out proj: x2 += ob @ outw^T  (split-K=2, atomic)
  gemm_bt_splitk<<<dim3(32, 8, 2), 256, 0, stream>>>(ob, outw_b, x2, 1024, 1024);

  // ln2 + seed d_out = x2 + b2
  ln_bf16_seed<<<4096, 256, 0, stream>>>(x2, ln2g, ln2b, xm, b2, (float*)d_out);

  // MLP up (writes hb, aliasing qkvb|ob — both dead now)
  gemm_bt<2><<<dim3(32, 32), 256, 0, stream>>>(xm, w1_b, b1, hb, 4096, 1024);

  // MLP down: d_out += hb @ w2^T  (split-K=2, atomic)
  gemm_bt_splitk<<<dim3(32, 8, 2), 256, 0, stream>>>(hb, w2_b, (float*)d_out, 1024, 4096);
}

// Round 5
// 327.411 us; speedup vs baseline: 1.0403x; 1.0210x over previous
//
#include <hip/hip_runtime.h>
#include <stdint.h>

// ---------------------------------------------------------------------------
// Types / helpers
// ---------------------------------------------------------------------------
typedef __bf16 bf16x8 __attribute__((ext_vector_type(8)));
typedef float  f32x4  __attribute__((ext_vector_type(4)));

__device__ __forceinline__ unsigned short f2bf(float f) {
  union { float f; unsigned int u; } a; a.f = f;
  unsigned int r = a.u + 0x7FFFu + ((a.u >> 16) & 1u);   // RNE
  return (unsigned short)(r >> 16);
}

__device__ __forceinline__ unsigned short f2bf_fast(float f) {
  union { __bf16 b; unsigned short u; } v; v.b = (__bf16)f; return v.u;
}

// async global->LDS, 16B per lane. LDS dest must be wave-uniform base + lane*16.
__device__ __forceinline__ void cp16(const void* g, void* l) {
  auto g1 = reinterpret_cast<__attribute__((address_space(1))) unsigned int*>(
      reinterpret_cast<uintptr_t>(g));
  auto l3 = reinterpret_cast<__attribute__((address_space(3))) unsigned int*>(
      reinterpret_cast<uintptr_t>(l));
  __builtin_amdgcn_global_load_lds(g1, l3, 16, 0, 0);
}

// ---------------------------------------------------------------------------
// Fused: weight fp32->bf16 convert (blocks 0..12287) AND ln1+seed (blocks
// 12288..16383). Independent work, one launch to cut a kernel gap.
// ---------------------------------------------------------------------------
__global__ __launch_bounds__(256) void cvt_ln1(
    const float* __restrict__ s0, const float* __restrict__ s1,
    const float* __restrict__ s2, const float* __restrict__ s3,
    unsigned short* __restrict__ d0, unsigned short* __restrict__ d1,
    unsigned short* __restrict__ d2, unsigned short* __restrict__ d3,
    const float* __restrict__ x,
    const float* __restrict__ g,
    const float* __restrict__ bta,
    unsigned short* __restrict__ out,
    const float* __restrict__ seed_bias,
    float* __restrict__ seed_out) {
  if (blockIdx.x < 12288) {
    int i = (blockIdx.x * 256 + threadIdx.x) * 4;
    const float* src; unsigned short* dst; int off;
    if (i < 3145728)       { src = s0; dst = d0; off = 0; }
    else if (i < 4194304)  { src = s1; dst = d1; off = 3145728; }
    else if (i < 8388608)  { src = s2; dst = d2; off = 4194304; }
    else                   { src = s3; dst = d3; off = 8388608; }
    i -= off;
    float4 v = *(const float4*)(src + i);
    union { unsigned short u[4]; uint2 p; } o;
    o.u[0] = f2bf(v.x); o.u[1] = f2bf(v.y); o.u[2] = f2bf(v.z); o.u[3] = f2bf(v.w);
    *(uint2*)(dst + i) = o.p;
    return;
  }
  const int row = blockIdx.x - 12288, t = threadIdx.x;
  const float4 v = *(const float4*)(x + (size_t)row * 1024 + t * 4);
  {
    float4 sb = *(const float4*)(seed_bias + t * 4);
    float4 sv;
    sv.x = v.x + sb.x; sv.y = v.y + sb.y; sv.z = v.z + sb.z; sv.w = v.w + sb.w;
    *(float4*)(seed_out + (size_t)row * 1024 + t * 4) = sv;
  }
  float s1v = v.x + v.y + v.z + v.w;
  float s2v = v.x*v.x + v.y*v.y + v.z*v.z + v.w*v.w;
  #pragma unroll
  for (int off = 1; off < 64; off <<= 1) {
    s1v += __shfl_xor(s1v, off, 64);
    s2v += __shfl_xor(s2v, off, 64);
  }
  __shared__ float r1[4], r2[4];
  if ((t & 63) == 0) { r1[t >> 6] = s1v; r2[t >> 6] = s2v; }
  __syncthreads();
  s1v = r1[0] + r1[1] + r1[2] + r1[3];
  s2v = r2[0] + r2[1] + r2[2] + r2[3];
  const float mean = s1v * (1.0f / 1024.0f);
  const float var  = s2v * (1.0f / 1024.0f) - mean * mean;
  const float rstd = rsqrtf(var + 1e-5f);
  const float4 gv = *(const float4*)(g + t * 4);
  const float4 bv = *(const float4*)(bta + t * 4);
  union { unsigned short u[4]; uint2 p; } o;
  o.u[0] = f2bf((v.x - mean) * rstd * gv.x + bv.x);
  o.u[1] = f2bf((v.y - mean) * rstd * gv.y + bv.y);
  o.u[2] = f2bf((v.z - mean) * rstd * gv.z + bv.z);
  o.u[3] = f2bf((v.w - mean) * rstd * gv.w + bv.w);
  *(uint2*)(out + (size_t)row * 1024 + t * 4) = o.p;
}

// ---------------------------------------------------------------------------
// LayerNorm (E=1024), fp32 in -> bf16 out, PLUS seeds the next GEMM's
// accumulator: seed_out[row,:] = x[row,:] + seed_bias[:].
// ---------------------------------------------------------------------------
__global__ __launch_bounds__(256) void ln_bf16_seed(
    const float* __restrict__ x,
    const float* __restrict__ g,
    const float* __restrict__ bta,
    unsigned short* __restrict__ out,
    const float* __restrict__ seed_bias,
    float* __restrict__ seed_out) {
  const int row = blockIdx.x, t = threadIdx.x;
  const float4 v = *(const float4*)(x + (size_t)row * 1024 + t * 4);
  {
    float4 sb = *(const float4*)(seed_bias + t * 4);
    float4 sv;
    sv.x = v.x + sb.x; sv.y = v.y + sb.y; sv.z = v.z + sb.z; sv.w = v.w + sb.w;
    *(float4*)(seed_out + (size_t)row * 1024 + t * 4) = sv;
  }
  float s1 = v.x + v.y + v.z + v.w;
  float s2 = v.x*v.x + v.y*v.y + v.z*v.z + v.w*v.w;
  #pragma unroll
  for (int off = 1; off < 64; off <<= 1) {
    s1 += __shfl_xor(s1, off, 64);
    s2 += __shfl_xor(s2, off, 64);
  }
  __shared__ float r1[4], r2[4];
  if ((t & 63) == 0) { r1[t >> 6] = s1; r2[t >> 6] = s2; }
  __syncthreads();
  s1 = r1[0] + r1[1] + r1[2] + r1[3];
  s2 = r2[0] + r2[1] + r2[2] + r2[3];
  const float mean = s1 * (1.0f / 1024.0f);
  const float var  = s2 * (1.0f / 1024.0f) - mean * mean;
  const float rstd = rsqrtf(var + 1e-5f);
  const float4 gv = *(const float4*)(g + t * 4);
  const float4 bv = *(const float4*)(bta + t * 4);
  union { unsigned short u[4]; uint2 p; } o;
  o.u[0] = f2bf((v.x - mean) * rstd * gv.x + bv.x);
  o.u[1] = f2bf((v.y - mean) * rstd * gv.y + bv.y);
  o.u[2] = f2bf((v.z - mean) * rstd * gv.z + bv.z);
  o.u[3] = f2bf((v.w - mean) * rstd * gv.w + bv.w);
  *(uint2*)(out + (size_t)row * 1024 + t * 4) = o.p;
}

// ---------------------------------------------------------------------------
// Pipelined GEMM core (R0 proven optimum: double-buffered LDS, vmcnt(8)
// steady / vmcnt(0) tail, raw s_barrier, 2 blocks/CU). Reverted from the
// R4 triple-buffer (neutral on splitk, -6us on the others).
// MODE 0 = bf16 v+bias; MODE 2 = bf16 relu(v+bias); MODE 4 = atomic fp32 +=v;
// MODE 5 = plain fp32 partial store (split-K without atomics).
// ---------------------------------------------------------------------------
template <int MODE>
__device__ __forceinline__ void gemm_core(
    const unsigned short* __restrict__ A,
    const unsigned short* __restrict__ Bt,
    const float* __restrict__ bias,
    void* __restrict__ outp,
    int N, int K, int kbeg, int kend,
    unsigned short* As, unsigned short* Bs) {   // each [2][128*64]
  const int tid = threadIdx.x;
  const int wave = tid >> 6, lane = tid & 63;
  const int q = lane >> 4, c = lane & 15;
  const int wm = (wave & 1) << 6, wn = (wave >> 1) << 6;
  const int m0 = blockIdx.x << 7, n0 = blockIdx.y << 7;

  const int srow = tid >> 3;                       // 0..31
  const int cg8  = ((tid & 7) ^ (srow & 7)) << 3;  // swizzled col chunk

  const unsigned short* gA = A  + (size_t)(m0 + srow) * K + cg8;
  const unsigned short* gB = Bt + (size_t)(n0 + srow) * K + cg8;
  const size_t rstep = (size_t)32 * K;

  auto issue = [&](int k0, int buf) {
    unsigned short* lA = As + buf * 8192 + tid * 8;
    unsigned short* lB = Bs + buf * 8192 + tid * 8;
    #pragma unroll
    for (int it = 0; it < 4; it++) {
      cp16(gA + it * rstep + k0, lA + it * 2048);
      cp16(gB + it * rstep + k0, lB + it * 2048);
    }
  };

  const f32x4 fzero = {0.f, 0.f, 0.f, 0.f};
  f32x4 acc[4][4];
  #pragma unroll
  for (int i = 0; i < 4; i++)
    #pragma unroll
    for (int j = 0; j < 4; j++) acc[i][j] = fzero;

  issue(kbeg, 0);
  if (kbeg + 64 < kend) issue(kbeg + 64, 1);

  int buf = 0;
  for (int k0 = kbeg; k0 < kend; k0 += 64, buf ^= 1) {
    if (k0 + 64 < kend) asm volatile("s_waitcnt vmcnt(8)" ::: "memory");
    else                asm volatile("s_waitcnt vmcnt(0)" ::: "memory");
    asm volatile("s_barrier" ::: "memory");

    const unsigned short* cA = As + buf * 8192;
    const unsigned short* cB = Bs + buf * 8192;
    #pragma unroll
    for (int ks = 0; ks < 2; ks++) {
      const int sw = (((ks << 2) + q) ^ (c & 7)) << 3;
      bf16x8 af[4], bf[4];
      #pragma unroll
      for (int i = 0; i < 4; i++) af[i] = *(const bf16x8*)&cA[(wm + i*16 + c)*64 + sw];
      #pragma unroll
      for (int j = 0; j < 4; j++) bf[j] = *(const bf16x8*)&cB[(wn + j*16 + c)*64 + sw];
      #pragma unroll
      for (int i = 0; i < 4; i++)
        #pragma unroll
        for (int j = 0; j < 4; j++)
          acc[i][j] = __builtin_amdgcn_mfma_f32_16x16x32_bf16(af[i], bf[j], acc[i][j], 0, 0, 0);
    }

    asm volatile("s_barrier" ::: "memory");
    if (k0 + 128 < kend) issue(k0 + 128, buf);
  }

  if (MODE == 4) {
    float* op = (float*)outp;
    #pragma unroll
    for (int i = 0; i < 4; i++) {
      #pragma unroll
      for (int r = 0; r < 4; r++) {
        const int row = m0 + wm + i * 16 + q * 4 + r;
        #pragma unroll
        for (int j = 0; j < 4; j++) {
          const int col = n0 + wn + j * 16 + c;
          atomicAdd(op + (size_t)row * N + col, acc[i][j][r]);
        }
      }
    }
  } else if (MODE == 5) {
    float* op = (float*)outp;
    #pragma unroll
    for (int i = 0; i < 4; i++) {
      #pragma unroll
      for (int r = 0; r < 4; r++) {
        const int row = m0 + wm + i * 16 + q * 4 + r;
        #pragma unroll
        for (int j = 0; j < 4; j++) {
          const int col = n0 + wn + j * 16 + c;
          op[(size_t)row * N + col] = acc[i][j][r];
        }
      }
    }
  } else {
    float bj[4];
    #pragma unroll
    for (int j = 0; j < 4; j++) bj[j] = bias[n0 + wn + j * 16 + c];
    #pragma unroll
    for (int i = 0; i < 4; i++) {
      #pragma unroll
      for (int r = 0; r < 4; r++) {
        const int row = m0 + wm + i * 16 + q * 4 + r;
        #pragma unroll
        for (int j = 0; j < 4; j++) {
          const int col = n0 + wn + j * 16 + c;
          const size_t idx = (size_t)row * N + col;
          float v = acc[i][j][r] + bj[j];
          if (MODE == 0) ((unsigned short*)outp)[idx] = f2bf(v);
          else           ((unsigned short*)outp)[idx] = f2bf(fmaxf(v, 0.f));
        }
      }
    }
  }
}

template <int MODE>
__global__ __launch_bounds__(256, 2) void gemm_bt(
    const unsigned short* __restrict__ A,
    const unsigned short* __restrict__ Bt,
    const float* __restrict__ bias,
    void* __restrict__ outp,
    int N, int K) {
  __shared__ __align__(16) unsigned short As[2 * 8192];
  __shared__ __align__(16) unsigned short Bs[2 * 8192];
  gemm_core<MODE>(A, Bt, bias, outp, N, K, 0, K, As, Bs);
}

// split-K=2 with atomicAdd into pre-seeded fp32 output (control: out-proj)
__global__ __launch_bounds__(256, 2) void gemm_bt_splitk(
    const unsigned short* __restrict__ A,
    const unsigned short* __restrict__ Bt,
    float* __restrict__ outp,
    int N, int K) {
  __shared__ __align__(16) unsigned short As[2 * 8192];
  __shared__ __align__(16) unsigned short Bs[2 * 8192];
  const int KH = K >> 1;
  const int kbeg = blockIdx.z * KH;
  gemm_core<4>(A, Bt, nullptr, outp, N, K, kbeg, kbeg + KH, As, Bs);
}

// split-K=2 WITHOUT atomics: z writes its partial to Qz with plain stores.
__global__ __launch_bounds__(256, 2) void gemm_bt_splitk_p(
    const unsigned short* __restrict__ A,
    const unsigned short* __restrict__ Bt,
    float* __restrict__ Q0,
    float* __restrict__ Q1,
    int N, int K) {
  __shared__ __align__(16) unsigned short As[2 * 8192];
  __shared__ __align__(16) unsigned short Bs[2 * 8192];
  const int KH = K >> 1;
  const int kbeg = blockIdx.z * KH;
  gemm_core<5>(A, Bt, nullptr, blockIdx.z ? Q1 : Q0, N, K, kbeg, kbeg + KH, As, Bs);
}

// d_out += Q0 + Q1 (fp32, 4096x1024). 2048 blocks x 256 thr x f32x4 x 2 iter.
__global__ __launch_bounds__(256) void fold2(
    const float* __restrict__ Q0,
    const float* __restrict__ Q1,
    float* __restrict__ out) {
  int i = (blockIdx.x * 256 + threadIdx.x) * 4;
  #pragma unroll
  for (int it = 0; it < 2; it++) {
    float4 a  = *(const float4*)(out + i);
    float4 q0 = *(const float4*)(Q0 + i);
    float4 q1 = *(const float4*)(Q1 + i);
    a.x += q0.x + q1.x; a.y += q0.y + q1.y;
    a.z += q0.z + q1.z; a.w += q0.w + q1.w;
    *(float4*)(out + i) = a;
    i += 2097152;
  }
}

// ---------------------------------------------------------------------------
// Flash attention, causal + rel_pos bias (round-5 proven version, verbatim).
// ---------------------------------------------------------------------------
__global__ __launch_bounds__(256, 2) void attn_flash(
    const unsigned short* __restrict__ qkv,   // [4096, 3072] bf16 (q|k|v)
    const float* __restrict__ rel_pos,        // [16, 2048] fp32
    unsigned short* __restrict__ o) {         // [4096, 1024] bf16 ([b,s,h,d])
  __shared__ __align__(16) unsigned short Qs[128 * 64];
  __shared__ __align__(16) unsigned short Ks[64 * 64];
  __shared__ __align__(16) unsigned short Vs[64 * 64];   // transposed [d][kt]
  __shared__ __align__(16) unsigned short Ps[4][32 * 64];
  __shared__ float rps[1024];                            // rel_pos[h,:]*log2e

  const int tid = threadIdx.x;
  const int wave = tid >> 6, lane = tid & 63;
  const int q = lane >> 4, c = lane & 15;

  const int lid = blockIdx.x + (blockIdx.y << 3);
  const int xq = lid & 7, y = lid >> 3;
  const int qt = (y & 32) ? (7 - xq) : xq;
  const int b = y >> 4, h = y & 15;

  const unsigned short* qg = qkv + (size_t)b * 1024 * 3072 + h * 64;
  const unsigned short* kg = qg + 1024;
  const unsigned short* vg = qg + 2048;

  #pragma unroll
  for (int i = 0; i < 4; i++) {
    const int idx = tid + i * 256;
    rps[idx & 1023] = rel_pos[h * 2048 + (idx & 1023)] * 1.44269504f;
  }

  const int sr  = tid >> 3;
  const int cg8 = ((tid & 7) ^ (sr & 7)) << 3;
  #pragma unroll
  for (int it = 0; it < 4; it++)
    cp16(qg + (size_t)(qt * 128 + sr + it * 32) * 3072 + cg8, &Qs[(tid + it * 256) * 8]);
  __syncthreads();

  bf16x8 qf[2][2];
  #pragma unroll
  for (int mt = 0; mt < 2; mt++)
    #pragma unroll
    for (int ks = 0; ks < 2; ks++)
      qf[mt][ks] = *(const bf16x8*)&Qs[(wave*32 + mt*16 + c)*64 + ((((ks<<2)+q) ^ (c & 7)) << 3)];

  const f32x4 fzero = {0.f, 0.f, 0.f, 0.f};
  f32x4 O[2][4];
  float l_i[2][4];
  #pragma unroll
  for (int mt = 0; mt < 2; mt++) {
    #pragma unroll
    for (int r = 0; r < 4; r++) l_i[mt][r] = 0.f;
    #pragma unroll
    for (int dt = 0; dt < 4; dt++) O[mt][dt] = fzero;
  }

  unsigned short* Pw = &Ps[wave][0];
  const int i_base = qt * 128 + wave * 32;
  const int vrow = tid & 63, d0 = (tid >> 6) << 4;
  const int vchunk = vrow >> 3, vlo = vrow & 7;

  const float sc = 0.125f * 1.44269504f;
  const int kdiag = qt << 1;
  const int nkt = (qt + 1) * 2;

  for (int kt = 0; kt < nkt; kt++) {
    __syncthreads();
    cp16(kg + (size_t)(kt * 64 + sr) * 3072 + cg8, &Ks[tid * 8]);
    cp16(kg + (size_t)(kt * 64 + sr + 32) * 3072 + cg8, &Ks[(tid + 256) * 8]);
    {
      union { int4 v; unsigned short u[8]; } va, vb2;
      const unsigned short* vrp = vg + (size_t)(kt * 64 + vrow) * 3072 + d0;
      va.v  = *(const int4*)vrp;
      vb2.v = *(const int4*)(vrp + 8);
      #pragma unroll
      for (int j = 0; j < 8; j++) {
        const int pos = ((vchunk ^ j) << 3) + vlo;
        Vs[(d0 + j) * 64 + pos]     = va.u[j];
        Vs[(d0 + 8 + j) * 64 + pos] = vb2.u[j];
      }
    }
    __syncthreads();

    f32x4 S[2][4];
    #pragma unroll
    for (int mt = 0; mt < 2; mt++)
      #pragma unroll
      for (int nt = 0; nt < 4; nt++) S[mt][nt] = fzero;
    #pragma unroll
    for (int ks = 0; ks < 2; ks++) {
      const int sw = (((ks << 2) + q) ^ (c & 7)) << 3;
      bf16x8 kb[4];
      #pragma unroll
      for (int nt = 0; nt < 4; nt++) kb[nt] = *(const bf16x8*)&Ks[(nt*16 + c)*64 + sw];
      #pragma unroll
      for (int mt = 0; mt < 2; mt++)
        #pragma unroll
        for (int nt = 0; nt < 4; nt++)
          S[mt][nt] = __builtin_amdgcn_mfma_f32_16x16x32_bf16(qf[mt][ks], kb[nt], S[mt][nt], 0, 0, 0);
    }

    if (kt < kdiag) {
      #pragma unroll
      for (int mt = 0; mt < 2; mt++) {
        #pragma unroll
        for (int r = 0; r < 4; r++) {
          const int i_ = i_base + mt * 16 + q * 4 + r;
          const int prow = (mt * 16 + q * 4 + r) * 64;
          const int rsw  = (q * 4 + r) & 7;
          float s = 0.f;
          #pragma unroll
          for (int nt = 0; nt < 4; nt++) {
            const int j_ = kt * 64 + nt * 16 + c;
            const float p = exp2f(fmaf(S[mt][nt][r], sc, rps[i_ - j_]));
            s += p;
            Pw[prow + ((((nt << 1) + (c >> 3)) ^ rsw) << 3) + (c & 7)] = f2bf_fast(p);
          }
          l_i[mt][r] += s;
        }
      }
    } else {
      #pragma unroll
      for (int mt = 0; mt < 2; mt++) {
        #pragma unroll
        for (int r = 0; r < 4; r++) {
          const int i_ = i_base + mt * 16 + q * 4 + r;
          const int prow = (mt * 16 + q * 4 + r) * 64;
          const int rsw  = (q * 4 + r) & 7;
          float s = 0.f;
          #pragma unroll
          for (int nt = 0; nt < 4; nt++) {
            const int j_ = kt * 64 + nt * 16 + c;
            const int d_ = i_ - j_;
            const float p = (d_ >= 0)
                ? exp2f(fmaf(S[mt][nt][r], sc, rps[d_ & 1023])) : 0.f;
            s += p;
            Pw[prow + ((((nt << 1) + (c >> 3)) ^ rsw) << 3) + (c & 7)] = f2bf_fast(p);
          }
          l_i[mt][r] += s;
        }
      }
    }

    asm volatile("s_waitcnt lgkmcnt(0)" ::: "memory");

    #pragma unroll
    for (int ks = 0; ks < 2; ks++) {
      const int sw = (((ks << 2) + q) ^ (c & 7)) << 3;
      bf16x8 pa[2], vb[4];
      #pragma unroll
      for (int mt = 0; mt < 2; mt++) pa[mt] = *(const bf16x8*)&Pw[(mt*16 + c)*64 + sw];
      #pragma unroll
      for (int dt = 0; dt < 4; dt++) vb[dt] = *(const bf16x8*)&Vs[(dt*16 + c)*64 + sw];
      #pragma unroll
      for (int mt = 0; mt < 2; mt++)
        #pragma unroll
        for (int dt = 0; dt < 4; dt++)
          O[mt][dt] = __builtin_amdgcn_mfma_f32_16x16x32_bf16(pa[mt], vb[dt], O[mt][dt], 0, 0, 0);
    }
  }

  #pragma unroll
  for (int mt = 0; mt < 2; mt++) {
    #pragma unroll
    for (int r = 0; r < 4; r++) {
      float l = l_i[mt][r];
      l += __shfl_xor(l, 1, 64);
      l += __shfl_xor(l, 2, 64);
      l += __shfl_xor(l, 4, 64);
      l += __shfl_xor(l, 8, 64);
      const float inv = 1.0f / l;
      const int i_ = i_base + mt * 16 + q * 4 + r;
      unsigned short* orow = o + (size_t)(b * 1024 + i_) * 1024 + h * 64 + c;
      #pragma unroll
      for (int dt = 0; dt < 4; dt++) orow[dt * 16] = f2bf(O[mt][dt][r] * inv);
    }
  }
}

// ---------------------------------------------------------------------------
// Launch. Workspace ~81 MB, aliased. MLP-down partials Q0/Q1 alias DEAD
// regions at down-launch time:
//   Q0 = [ipw_b..w1_b] (6.29+2.10+8.39 = 16.78 MB, dead after QKV/out-proj/up)
//   Q1 = x2 (16.78 MB, dead after ln2)
// ---------------------------------------------------------------------------
extern "C" void kernel_launch(void* const* d_in, const int* in_sizes, int n_in,
                              void* d_out, int out_size, void* d_ws, size_t ws_size,
                              hipStream_t stream) {
  (void)in_sizes; (void)n_in; (void)out_size; (void)ws_size;
  const float* x    = (const float*)d_in[0];
  const float* rel  = (const float*)d_in[1];
  const float* ipw  = (const float*)d_in[2];
  const float* ipb  = (const float*)d_in[3];
  const float* outw = (const float*)d_in[4];
  const float* outb = (const float*)d_in[5];
  const float* w1   = (const float*)d_in[6];
  const float* b1   = (const float*)d_in[7];
  const float* w2   = (const float*)d_in[8];
  const float* b2   = (const float*)d_in[9];
  const float* ln1g = (const float*)d_in[10];
  const float* ln1b = (const float*)d_in[11];
  const float* ln2g = (const float*)d_in[12];
  const float* ln2b = (const float*)d_in[13];

  // workspace layout (elements), aliased:
  unsigned short* ipw_b  = (unsigned short*)d_ws;            // 3072*1024
  unsigned short* outw_b = ipw_b  + (size_t)3072 * 1024;     // 1024*1024
  unsigned short* w1_b   = outw_b + (size_t)1024 * 1024;     // 4096*1024
  unsigned short* w2_b   = w1_b   + (size_t)4096 * 1024;     // 1024*4096
  unsigned short* xn     = w2_b   + (size_t)1024 * 4096;     // 4096*1024 (also xm)
  unsigned short* qkvb   = xn     + (size_t)4096 * 1024;     // 4096*3072 ┐
  unsigned short* ob     = qkvb   + (size_t)4096 * 3072;     // 4096*1024 ┴ hb aliases both
  unsigned short* hb     = qkvb;                             // 4096*4096 (after out-proj)
  unsigned short* xm     = xn;                               // after QKV consumed xn
  float*          x2     = (float*)(ob + (size_t)4096 * 1024);  // 4096*1024 f32
  // MLP-down partials (aliases of dead regions at down-launch):
  float*          Q0     = (float*)d_ws;   // over ipw_b+outw_b+w1_b = 16.78 MB
  float*          Q1     = x2;             // x2 dead after ln2
  // total = 81 MB

  // fused: weight converts + ln1 + seed x2 = x + outb
  cvt_ln1<<<16384, 256, 0, stream>>>(ipw, outw, w1, w2, ipw_b, outw_b, w1_b, w2_b,
                                     x, ln1g, ln1b, xn, outb, x2);

  // QKV proj
  gemm_bt<0><<<dim3(32, 24), 256, 0, stream>>>(xn, ipw_b, ipb, qkvb, 3072, 1024);

  attn_flash<<<dim3(8, 64), 256, 0, stream>>>(qkvb, rel, ob);

  // attn out proj: x2 += ob @ outw^T  (split-K=2, atomic — control arm)
  gemm_bt_splitk<<<dim3(32, 8, 2), 256, 0, stream>>>(ob, outw_b, x2, 1024, 1024);

  // ln2 + seed d_out = x2 + b2
  ln_bf16_seed<<<4096, 256, 0, stream>>>(x2, ln2g, ln2b, xm, b2, (float*)d_out);

  // MLP up (writes hb, aliasing qkvb|ob — both dead now)
  gemm_bt<2><<<dim3(32, 32), 256, 0, stream>>>(xm, w1_b, b1, hb, 4096, 1024);

  // MLP down, atomic-free: partials Q0/Q1, then d_out += Q0 + Q1
  gemm_bt_splitk_p<<<dim3(32, 8, 2), 256, 0, stream>>>(hb, w2_b, Q0, Q1, 1024, 4096);
  fold2<<<2048, 256, 0, stream>>>(Q0, Q1, (float*)d_out);
}